// Round 1
// baseline (354.534 us; speedup 1.0000x reference)
//
#include <hip/hip_runtime.h>

typedef unsigned short u16;
typedef __bf16 bf16x8 __attribute__((ext_vector_type(8)));
typedef float f32x4 __attribute__((ext_vector_type(4)));

#define DIM 1024
#define NH 16
#define HD 64

__device__ __forceinline__ u16 f2bf(float f) {
  union { float f; unsigned u; } v; v.f = f;
  unsigned r = v.u + 0x7fffu + ((v.u >> 16) & 1u);
  return (u16)(r >> 16);
}

// ---------------- LayerNorm: fp32 row -> bf16 row ----------------
__global__ __launch_bounds__(256) void ln_kernel(const float* __restrict__ x,
    const float* __restrict__ g, const float* __restrict__ be, u16* __restrict__ out) {
  int row = blockIdx.x;
  const float* xr = x + (size_t)row * DIM;
  int tid = threadIdx.x;
  float v[4], s1 = 0.f, s2 = 0.f;
#pragma unroll
  for (int i = 0; i < 4; ++i) { v[i] = xr[tid + i * 256]; s1 += v[i]; s2 += v[i] * v[i]; }
#pragma unroll
  for (int o = 32; o >= 1; o >>= 1) { s1 += __shfl_xor(s1, o, 64); s2 += __shfl_xor(s2, o, 64); }
  __shared__ float red[2][4];
  int wv = tid >> 6;
  if ((tid & 63) == 0) { red[0][wv] = s1; red[1][wv] = s2; }
  __syncthreads();
  s1 = red[0][0] + red[0][1] + red[0][2] + red[0][3];
  s2 = red[1][0] + red[1][1] + red[1][2] + red[1][3];
  float mu = s1 * (1.f / DIM);
  float var = s2 * (1.f / DIM) - mu * mu;
  float rs = rsqrtf(var + 1e-5f);
  u16* orow = out + (size_t)row * DIM;
#pragma unroll
  for (int i = 0; i < 4; ++i) {
    int c = tid + i * 256;
    orow[c] = f2bf((v[i] - mu) * rs * g[c] + be[c]);
  }
}

// ---------------- Weight transpose + cast: W[k][n] fp32 -> Wt[n][k] bf16 ----------------
__global__ __launch_bounds__(256) void wtrans_kernel(const float* W0, const float* W1,
    const float* W2, const float* W3, u16* O0, u16* O1, u16* O2, u16* O3) {
  const float* W = blockIdx.z == 0 ? W0 : blockIdx.z == 1 ? W1 : blockIdx.z == 2 ? W2 : W3;
  u16* O        = blockIdx.z == 0 ? O0 : blockIdx.z == 1 ? O1 : blockIdx.z == 2 ? O2 : O3;
  __shared__ float t[32][33];
  int bx = blockIdx.x * 32, by = blockIdx.y * 32;
  int tx = threadIdx.x & 31, ty = threadIdx.x >> 5;
#pragma unroll
  for (int i = 0; i < 4; ++i) t[ty + i * 8][tx] = W[(size_t)(by + ty + i * 8) * DIM + bx + tx];
  __syncthreads();
#pragma unroll
  for (int i = 0; i < 4; ++i) O[(size_t)(bx + ty + i * 8) * DIM + by + tx] = f2bf(t[tx][ty + i * 8]);
}

// ---------------- bf16 MFMA GEMM: C[M,N] = A[M,K] @ Bt[N,K]^T + bias ----------------
// MODE 0: bf16 out row-major (K proj)
// MODE 1: bf16 out row-major, *0.125 (Q proj, score scale folded)
// MODE 2: bf16 out transposed per batch: out[(b*1024 + n)*2048 + t] (V proj -> Vt)
// MODE 3: fp32 out row-major + residual (O proj)
template<int MODE>
__global__ __launch_bounds__(256) void gemm_kernel(const u16* __restrict__ A,
    const u16* __restrict__ Bt, const float* __restrict__ bias, void* __restrict__ outp,
    const float* __restrict__ resid, int M, int N, int Kd) {
  __shared__ __align__(16) u16 As[64][72];
  __shared__ __align__(16) u16 Bs[64][72];
  int tid = threadIdx.x;
  int wave = tid >> 6, lane = tid & 63, lr = lane & 15, quad = lane >> 4;
  int m0 = blockIdx.x * 64, n0 = blockIdx.y * 64;
  int wm = (wave >> 1) * 32, wn = (wave & 1) * 32;
  f32x4 acc[2][2] = {};
  for (int kt = 0; kt < Kd; kt += 64) {
#pragma unroll
    for (int i = 0; i < 2; ++i) {
      int s = tid + i * 256;
      int r = s >> 3, c = (s & 7) * 8;
      *(uint4*)&As[r][c] = *(const uint4*)&A[(size_t)(m0 + r) * Kd + kt + c];
      *(uint4*)&Bs[r][c] = *(const uint4*)&Bt[(size_t)(n0 + r) * Kd + kt + c];
    }
    __syncthreads();
#pragma unroll
    for (int kc = 0; kc < 2; ++kc) {
      bf16x8 af[2], bf_[2];
#pragma unroll
      for (int i = 0; i < 2; ++i) {
        af[i]  = *(const bf16x8*)&As[wm + i * 16 + lr][kc * 32 + quad * 8];
        bf_[i] = *(const bf16x8*)&Bs[wn + i * 16 + lr][kc * 32 + quad * 8];
      }
#pragma unroll
      for (int mi = 0; mi < 2; ++mi)
#pragma unroll
        for (int ni = 0; ni < 2; ++ni)
          acc[mi][ni] = __builtin_amdgcn_mfma_f32_16x16x32_bf16(af[mi], bf_[ni], acc[mi][ni], 0, 0, 0);
    }
    __syncthreads();
  }
#pragma unroll
  for (int mi = 0; mi < 2; ++mi)
#pragma unroll
    for (int ni = 0; ni < 2; ++ni) {
      int col = n0 + wn + ni * 16 + lr;
      float bv = bias[col];
      if (MODE == 2) {
        int row0 = m0 + wm + mi * 16 + quad * 4;
        int bb = row0 >> 11, t0 = row0 & 2047;
        unsigned long long pk = 0;
#pragma unroll
        for (int r = 0; r < 4; ++r) {
          float vv = acc[mi][ni][r] + bv;
          pk |= (unsigned long long)f2bf(vv) << (16 * r);
        }
        *(unsigned long long*)&((u16*)outp)[((size_t)(bb << 10) + col) * 2048 + t0] = pk;
      } else {
#pragma unroll
        for (int r = 0; r < 4; ++r) {
          int row = m0 + wm + mi * 16 + quad * 4 + r;
          float vv = acc[mi][ni][r] + bv;
          if (MODE == 1) vv *= 0.125f;
          if (MODE == 0 || MODE == 1)
            ((u16*)outp)[(size_t)row * N + col] = f2bf(vv);
          else if (MODE == 3)
            ((float*)outp)[(size_t)row * N + col] = vv + resid[(size_t)row * N + col];
        }
      }
    }
}

// ---------------- Flash attention (online softmax), 64 Q-rows/block ----------------
// Q,K: [B*2048, 1024] bf16 row-major (Q pre-scaled by 0.125). Vt: [(b*1024+n), 2048] bf16.
__global__ __launch_bounds__(256) void flash_kernel(const u16* __restrict__ Q,
    const u16* __restrict__ Kg, const u16* __restrict__ Vt, u16* __restrict__ AO) {
  __shared__ __align__(16) u16 Qs[64][72];
  __shared__ __align__(16) u16 Ks[64][72];
  __shared__ __align__(16) u16 Vs[64][72];
  __shared__ __align__(16) u16 Ps[4][16][72];
  int tid = threadIdx.x, wave = tid >> 6, lane = tid & 63;
  int lr = lane & 15, quad = lane >> 4;
  int bh = blockIdx.y, b = bh >> 4, h = bh & 15;
  int q0 = blockIdx.x * 64;
#pragma unroll
  for (int i = 0; i < 2; ++i) {
    int s = tid + i * 256, r = s >> 3, c = (s & 7) * 8;
    *(uint4*)&Qs[r][c] = *(const uint4*)&Q[((size_t)(b * 2048 + q0 + r)) * DIM + h * HD + c];
  }
  __syncthreads();
  bf16x8 aq[2];
  aq[0] = *(const bf16x8*)&Qs[wave * 16 + lr][quad * 8];
  aq[1] = *(const bf16x8*)&Qs[wave * 16 + lr][32 + quad * 8];
  float mrow[4], lrow[4];
  f32x4 oacc[4] = {};
#pragma unroll
  for (int r = 0; r < 4; ++r) { mrow[r] = -1e30f; lrow[r] = 0.f; }
  for (int j0 = 0; j0 < 2048; j0 += 64) {
#pragma unroll
    for (int i = 0; i < 2; ++i) {
      int s = tid + i * 256, r = s >> 3, c = (s & 7) * 8;
      *(uint4*)&Ks[r][c] = *(const uint4*)&Kg[((size_t)(b * 2048 + j0 + r)) * DIM + h * HD + c];
      *(uint4*)&Vs[r][c] = *(const uint4*)&Vt[((size_t)(b * 1024 + h * HD + r)) * 2048 + j0 + c];
    }
    __syncthreads();
    f32x4 sf[4] = {};
#pragma unroll
    for (int ns = 0; ns < 4; ++ns)
#pragma unroll
      for (int kc = 0; kc < 2; ++kc) {
        bf16x8 bkf = *(const bf16x8*)&Ks[ns * 16 + lr][kc * 32 + quad * 8];
        sf[ns] = __builtin_amdgcn_mfma_f32_16x16x32_bf16(aq[kc], bkf, sf[ns], 0, 0, 0);
      }
    float pv[4][4];
#pragma unroll
    for (int r = 0; r < 4; ++r) {
      float rm = fmaxf(fmaxf(sf[0][r], sf[1][r]), fmaxf(sf[2][r], sf[3][r]));
#pragma unroll
      for (int o = 1; o < 16; o <<= 1) rm = fmaxf(rm, __shfl_xor(rm, o, 64));
      float mnew = fmaxf(mrow[r], rm);
      float alpha = __expf(mrow[r] - mnew);
      mrow[r] = mnew;
      float rsum = 0.f;
#pragma unroll
      for (int ns = 0; ns < 4; ++ns) { float p = __expf(sf[ns][r] - mnew); pv[ns][r] = p; rsum += p; }
#pragma unroll
      for (int o = 1; o < 16; o <<= 1) rsum += __shfl_xor(rsum, o, 64);
      lrow[r] = lrow[r] * alpha + rsum;
#pragma unroll
      for (int ds = 0; ds < 4; ++ds) oacc[ds][r] *= alpha;
    }
#pragma unroll
    for (int ns = 0; ns < 4; ++ns)
#pragma unroll
      for (int r = 0; r < 4; ++r)
        Ps[wave][quad * 4 + r][ns * 16 + lr] = f2bf(pv[ns][r]);
#pragma unroll
    for (int kc = 0; kc < 2; ++kc) {
      bf16x8 ap = *(const bf16x8*)&Ps[wave][lr][kc * 32 + quad * 8];
#pragma unroll
      for (int ds = 0; ds < 4; ++ds) {
        bf16x8 bvf = *(const bf16x8*)&Vs[ds * 16 + lr][kc * 32 + quad * 8];
        oacc[ds] = __builtin_amdgcn_mfma_f32_16x16x32_bf16(ap, bvf, oacc[ds], 0, 0, 0);
      }
    }
    __syncthreads();
  }
#pragma unroll
  for (int ds = 0; ds < 4; ++ds)
#pragma unroll
    for (int r = 0; r < 4; ++r) {
      float vv = oacc[ds][r] / lrow[r];
      AO[((size_t)(b * 2048 + q0 + wave * 16 + quad * 4 + r)) * DIM + h * HD + ds * 16 + lr] = f2bf(vv);
    }
}

extern "C" void kernel_launch(void* const* d_in, const int* in_sizes, int n_in,
                              void* d_out, int out_size, void* d_ws, size_t ws_size,
                              hipStream_t stream) {
  const float* query   = (const float*)d_in[0];
  const float* context = (const float*)d_in[1];
  const float* Wq = (const float*)d_in[2];
  const float* bq = (const float*)d_in[3];
  const float* Wk = (const float*)d_in[4];
  const float* bk = (const float*)d_in[5];
  const float* Wv = (const float*)d_in[6];
  const float* bv = (const float*)d_in[7];
  const float* Wo = (const float*)d_in[8];
  const float* bo = (const float*)d_in[9];
  const float* gq    = (const float*)d_in[10];
  const float* betaq = (const float*)d_in[11];
  const float* gkv   = (const float*)d_in[12];
  const float* betakv= (const float*)d_in[13];
  (void)in_sizes; (void)n_in; (void)out_size; (void)ws_size;

  char* ws = (char*)d_ws;
  const size_t MB = (size_t)1 << 20;
  u16* qn  = (u16*)(ws + 0 * MB);   // 4096x1024 bf16 (8 MB)
  u16* cn  = (u16*)(ws + 8 * MB);   // 8 MB
  u16* Wqt = (u16*)(ws + 16 * MB);  // 2 MB each
  u16* Wkt = (u16*)(ws + 18 * MB);
  u16* Wvt = (u16*)(ws + 20 * MB);
  u16* Wot = (u16*)(ws + 22 * MB);
  u16* Qb  = (u16*)(ws + 24 * MB);  // 8 MB
  u16* Kb  = (u16*)(ws + 32 * MB);  // 8 MB
  u16* Vtb = (u16*)(ws + 40 * MB);  // 8 MB
  u16* AOb = (u16*)(ws + 48 * MB);  // 8 MB  (total 56 MB)

  ln_kernel<<<4096, 256, 0, stream>>>(query, gq, betaq, qn);
  ln_kernel<<<4096, 256, 0, stream>>>(context, gkv, betakv, cn);
  wtrans_kernel<<<dim3(32, 32, 4), 256, 0, stream>>>(Wq, Wk, Wv, Wo, Wqt, Wkt, Wvt, Wot);
  gemm_kernel<1><<<dim3(64, 16), 256, 0, stream>>>(qn, Wqt, bq, (void*)Qb,  nullptr, 4096, 1024, 1024);
  gemm_kernel<0><<<dim3(64, 16), 256, 0, stream>>>(cn, Wkt, bk, (void*)Kb,  nullptr, 4096, 1024, 1024);
  gemm_kernel<2><<<dim3(64, 16), 256, 0, stream>>>(cn, Wvt, bv, (void*)Vtb, nullptr, 4096, 1024, 1024);
  flash_kernel<<<dim3(32, 32), 256, 0, stream>>>(Qb, Kb, Vtb, AOb);
  gemm_kernel<3><<<dim3(64, 16), 256, 0, stream>>>(AOb, Wot, bo, d_out, query, 4096, 1024, 1024);
}

// Round 2
// 286.319 us; speedup vs baseline: 1.2382x; 1.2382x over previous
//
#include <hip/hip_runtime.h>
#include <hip/hip_bf16.h>

typedef unsigned short u16;
typedef unsigned long long u64;
typedef __bf16 bf16x8 __attribute__((ext_vector_type(8)));
typedef float f32x4 __attribute__((ext_vector_type(4)));

#define DIM 1024
#define NH 16
#define HD 64
// 0.125 * log2(e): folds both the 1/sqrt(64) score scale and the exp->exp2 change of base
#define QSCALE 0.180336880972788f

__device__ __forceinline__ u16 f2bf(float f) {
  union { float f; unsigned u; } v; v.f = f;
  unsigned r = v.u + 0x7fffu + ((v.u >> 16) & 1u);
  return (u16)(r >> 16);
}

__device__ __forceinline__ unsigned pk2(float a, float b) {
  union { __hip_bfloat162 h; unsigned u; } cv;
  cv.h = __float22bfloat162_rn(make_float2(a, b));
  return cv.u;
}

__device__ __forceinline__ void gld16(const u16* gp, u16* lp) {
  __builtin_amdgcn_global_load_lds(
      (const __attribute__((address_space(1))) unsigned int*)(const void*)gp,
      (__attribute__((address_space(3))) unsigned int*)(void*)lp, 16, 0, 0);
}

// ---------------- LayerNorm: fp32 row -> bf16 row (vectorized) ----------------
__global__ __launch_bounds__(256) void ln_kernel(const float* __restrict__ x,
    const float* __restrict__ g, const float* __restrict__ be, u16* __restrict__ out) {
  int row = blockIdx.x, tid = threadIdx.x;
  float4 v = ((const float4*)(x + (size_t)row * DIM))[tid];
  float s1 = v.x + v.y + v.z + v.w;
  float s2 = v.x * v.x + v.y * v.y + v.z * v.z + v.w * v.w;
#pragma unroll
  for (int o = 32; o >= 1; o >>= 1) { s1 += __shfl_xor(s1, o, 64); s2 += __shfl_xor(s2, o, 64); }
  __shared__ float red[2][4];
  int wv = tid >> 6;
  if ((tid & 63) == 0) { red[0][wv] = s1; red[1][wv] = s2; }
  __syncthreads();
  s1 = red[0][0] + red[0][1] + red[0][2] + red[0][3];
  s2 = red[1][0] + red[1][1] + red[1][2] + red[1][3];
  float mu = s1 * (1.f / DIM);
  float var = s2 * (1.f / DIM) - mu * mu;
  float rs = rsqrtf(var + 1e-5f);
  float4 gv = ((const float4*)g)[tid];
  float4 bv = ((const float4*)be)[tid];
  uint2 o2;
  o2.x = pk2((v.x - mu) * rs * gv.x + bv.x, (v.y - mu) * rs * gv.y + bv.y);
  o2.y = pk2((v.z - mu) * rs * gv.z + bv.z, (v.w - mu) * rs * gv.w + bv.w);
  ((uint2*)(out + (size_t)row * DIM))[tid] = o2;
}

// ---------------- Weight transpose + cast: W[k][n] fp32 -> Wt[n][k] bf16 ----------------
__global__ __launch_bounds__(256) void wtrans_kernel(const float* W0, const float* W1,
    const float* W2, const float* W3, u16* O0, u16* O1, u16* O2, u16* O3) {
  const float* W = blockIdx.z == 0 ? W0 : blockIdx.z == 1 ? W1 : blockIdx.z == 2 ? W2 : W3;
  u16* O        = blockIdx.z == 0 ? O0 : blockIdx.z == 1 ? O1 : blockIdx.z == 2 ? O2 : O3;
  __shared__ float t[32][33];
  int bx = blockIdx.x * 32, by = blockIdx.y * 32;
  int tx = threadIdx.x & 31, ty = threadIdx.x >> 5;
#pragma unroll
  for (int i = 0; i < 4; ++i) t[ty + i * 8][tx] = W[(size_t)(by + ty + i * 8) * DIM + bx + tx];
  __syncthreads();
#pragma unroll
  for (int i = 0; i < 4; ++i) O[(size_t)(bx + ty + i * 8) * DIM + by + tx] = f2bf(t[tx][ty + i * 8]);
}

// ---------------- 128x128 bf16 MFMA GEMM (m97-style, global_load_lds, swizzled LDS) ----
// mode 0: bf16 row-major       (K proj)
// mode 1: bf16 row-major *QSCALE (Q proj)
// mode 2: bf16 transposed per batch: out[(b*1024+n)*2048 + t]  (V proj -> Vt)
// mode 3: fp32 row-major + bias + residual (O proj)
struct GArg { const u16* A; const u16* Bt; const float* bias; void* out; const float* resid; int mode; };
struct GArg3 { GArg g[3]; };

__global__ __launch_bounds__(256) void gemm128(GArg3 args) {
  GArg ga = args.g[blockIdx.z];
  const u16* __restrict__ A  = ga.A;
  const u16* __restrict__ Bt = ga.Bt;
  __shared__ __align__(16) u16 sm[128 * 64 * 2];
  u16* As = sm;
  u16* Bs = sm + 128 * 64;
  int tid = threadIdx.x, wave = tid >> 6, lane = tid & 63;
  int lr = lane & 15, quad = lane >> 4;
  int m0 = blockIdx.x * 128, n0 = blockIdx.y * 128;
  int wm = (wave >> 1) * 64, wn = (wave & 1) * 64;
  f32x4 acc[4][4] = {};
  for (int kt = 0; kt < DIM; kt += 64) {
#pragma unroll
    for (int r = 0; r < 4; ++r) {
      int slot = tid + r * 256;
      int row = slot >> 3;
      int c = (slot & 7) ^ (row & 7);
      gld16(A + (size_t)(m0 + row) * DIM + kt + c * 8, &As[slot * 8]);
    }
#pragma unroll
    for (int r = 0; r < 4; ++r) {
      int slot = tid + r * 256;
      int row = slot >> 3;
      int c = (slot & 7) ^ (row & 7);
      gld16(Bt + (size_t)(n0 + row) * DIM + kt + c * 8, &Bs[slot * 8]);
    }
    __syncthreads();
#pragma unroll
    for (int kc = 0; kc < 2; ++kc) {
      int pc = (((kc * 4 + quad) ^ (lr & 7)) * 8);
      bf16x8 af[4], bfr[4];
#pragma unroll
      for (int i = 0; i < 4; ++i) {
        af[i]  = *(const bf16x8*)&As[(wm + i * 16 + lr) * 64 + pc];
        bfr[i] = *(const bf16x8*)&Bs[(wn + i * 16 + lr) * 64 + pc];
      }
#pragma unroll
      for (int mi = 0; mi < 4; ++mi)
#pragma unroll
        for (int ni = 0; ni < 4; ++ni)
          acc[mi][ni] = __builtin_amdgcn_mfma_f32_16x16x32_bf16(af[mi], bfr[ni], acc[mi][ni], 0, 0, 0);
    }
    __syncthreads();
  }
  int mode = ga.mode;
  const float* bias = ga.bias;
#pragma unroll
  for (int mi = 0; mi < 4; ++mi)
#pragma unroll
    for (int ni = 0; ni < 4; ++ni) {
      int col = n0 + wn + ni * 16 + lr;
      float bv = bias[col];
      int row0 = m0 + wm + mi * 16 + quad * 4;
      if (mode == 2) {
        int bb = row0 >> 11, t0 = row0 & 2047;
        u64 pk = 0;
#pragma unroll
        for (int r = 0; r < 4; ++r)
          pk |= (u64)f2bf(acc[mi][ni][r] + bv) << (16 * r);
        *(u64*)&((u16*)ga.out)[((size_t)(bb << 10) + col) * 2048 + t0] = pk;
      } else if (mode == 3) {
#pragma unroll
        for (int r = 0; r < 4; ++r) {
          int row = row0 + r;
          ((float*)ga.out)[(size_t)row * DIM + col] =
              acc[mi][ni][r] + bv + ga.resid[(size_t)row * DIM + col];
        }
      } else {
        float sc = (mode == 1) ? QSCALE : 1.f;
#pragma unroll
        for (int r = 0; r < 4; ++r)
          ((u16*)ga.out)[(size_t)(row0 + r) * DIM + col] = f2bf((acc[mi][ni][r] + bv) * sc);
      }
    }
}

// ---------------- Flash attention, S^T form, no-max exp2 softmax ----------------
// Q,K: [B*2048,1024] bf16 (Q pre-scaled by QSCALE). Vt: [(b*1024+h*64+d)][token] bf16.
// Block: 128 threads (2 waves), 64 q-rows; wave handles 32 q (2 B-frag sets).
#define LK 0
#define LV 4096
#define LQ 8192  // Qs, aliased by Ps after Q-frags are hoisted
__global__ __launch_bounds__(128) void flash_kernel(const u16* __restrict__ Q,
    const u16* __restrict__ Kg, const u16* __restrict__ Vt, u16* __restrict__ AO) {
  __shared__ __align__(16) u16 lds[12288];
  int tid = threadIdx.x, wave = tid >> 6, lane = tid & 63;
  int lr = lane & 15, quad = lane >> 4;
  int bh = blockIdx.x, b = bh >> 4, h = bh & 15;
  int q0 = blockIdx.y * 64;

  const u16* qbase = Q + (size_t)(b * 2048 + q0) * DIM + h * HD;
#pragma unroll
  for (int r = 0; r < 4; ++r) {
    int slot = tid + r * 128;
    int row = slot >> 3;
    int c = (slot & 7) ^ (row & 7);
    gld16(qbase + (size_t)row * DIM + c * 8, &lds[LQ + slot * 8]);
  }
  __syncthreads();
  bf16x8 qf[2][2];
#pragma unroll
  for (int s = 0; s < 2; ++s)
#pragma unroll
    for (int kc = 0; kc < 2; ++kc)
      qf[s][kc] = *(const bf16x8*)&lds[LQ + (wave * 32 + s * 16 + lr) * 64 +
                                       (((kc * 4 + quad) ^ (lr & 7)) * 8)];

  const u16* kbase = Kg + (size_t)(b * 2048) * DIM + h * HD;
  const u16* vbase = Vt + (size_t)(b * 1024 + h * HD) * 2048;

  float plsum[2] = {0.f, 0.f};
  f32x4 oacc[2][4] = {};

  for (int j0 = 0; j0 < 2048; j0 += 64) {
#pragma unroll
    for (int r = 0; r < 4; ++r) {
      int slot = tid + r * 128;
      int row = slot >> 3;
      int c = (slot & 7) ^ (row & 7);
      gld16(kbase + (size_t)(j0 + row) * DIM + c * 8, &lds[LK + slot * 8]);
      gld16(vbase + (size_t)row * 2048 + j0 + c * 8, &lds[LV + slot * 8]);
    }
    __syncthreads();

    // S^T = K . Q^T  (A = K tile, B = Q frags)
    f32x4 sf[2][4] = {};
#pragma unroll
    for (int kc = 0; kc < 2; ++kc)
#pragma unroll
      for (int ns = 0; ns < 4; ++ns) {
        bf16x8 kf = *(const bf16x8*)&lds[LK + (ns * 16 + lr) * 64 +
                                         (((kc * 4 + quad) ^ (lr & 7)) * 8)];
#pragma unroll
        for (int s = 0; s < 2; ++s)
          sf[s][ns] = __builtin_amdgcn_mfma_f32_16x16x32_bf16(kf, qf[s][kc], sf[s][ns], 0, 0, 0);
      }

    // p = exp2(s'); pack 4 consecutive k per lane -> one 8B LDS write (per-wave slice of Ps)
#pragma unroll
    for (int s = 0; s < 2; ++s)
#pragma unroll
      for (int ns = 0; ns < 4; ++ns) {
        float p0 = exp2f(sf[s][ns][0]), p1 = exp2f(sf[s][ns][1]);
        float p2 = exp2f(sf[s][ns][2]), p3 = exp2f(sf[s][ns][3]);
        plsum[s] += (p0 + p1) + (p2 + p3);
        uint2 pk;
        pk.x = pk2(p0, p1);
        pk.y = pk2(p2, p3);
        int chunk = ns * 2 + (quad >> 1);
        int off = (wave * 32 + s * 16 + lr) * 64 + ((chunk ^ (lr & 7)) * 8) + (quad & 1) * 4;
        *(uint2*)&lds[LQ + off] = pk;
      }
    __threadfence_block();  // order intra-wave Ps write -> read (no cross-wave dependency)

    // O^T += V^T . P^T  (A = V tile, B = P frags)
#pragma unroll
    for (int kc = 0; kc < 2; ++kc) {
      int pc = (((kc * 4 + quad) ^ (lr & 7)) * 8);
      bf16x8 pf[2];
#pragma unroll
      for (int s = 0; s < 2; ++s)
        pf[s] = *(const bf16x8*)&lds[LQ + (wave * 32 + s * 16 + lr) * 64 + pc];
#pragma unroll
      for (int ds = 0; ds < 4; ++ds) {
        bf16x8 vf = *(const bf16x8*)&lds[LV + (ds * 16 + lr) * 64 + pc];
#pragma unroll
        for (int s = 0; s < 2; ++s)
          oacc[s][ds] = __builtin_amdgcn_mfma_f32_16x16x32_bf16(vf, pf[s], oacc[s][ds], 0, 0, 0);
      }
    }
    __syncthreads();
  }

#pragma unroll
  for (int s = 0; s < 2; ++s) {
    float l = plsum[s];
    l += __shfl_xor(l, 16, 64);
    l += __shfl_xor(l, 32, 64);
    float rl = 1.f / l;
    size_t qrow = (size_t)(b * 2048 + q0 + wave * 32 + s * 16 + lr);
#pragma unroll
    for (int ds = 0; ds < 4; ++ds) {
      uint2 pk;
      pk.x = pk2(oacc[s][ds][0] * rl, oacc[s][ds][1] * rl);
      pk.y = pk2(oacc[s][ds][2] * rl, oacc[s][ds][3] * rl);
      *(uint2*)&AO[qrow * DIM + h * HD + ds * 16 + quad * 4] = pk;
    }
  }
}

extern "C" void kernel_launch(void* const* d_in, const int* in_sizes, int n_in,
                              void* d_out, int out_size, void* d_ws, size_t ws_size,
                              hipStream_t stream) {
  const float* query   = (const float*)d_in[0];
  const float* context = (const float*)d_in[1];
  const float* Wq = (const float*)d_in[2];
  const float* bq = (const float*)d_in[3];
  const float* Wk = (const float*)d_in[4];
  const float* bk = (const float*)d_in[5];
  const float* Wv = (const float*)d_in[6];
  const float* bv = (const float*)d_in[7];
  const float* Wo = (const float*)d_in[8];
  const float* bo = (const float*)d_in[9];
  const float* gq    = (const float*)d_in[10];
  const float* betaq = (const float*)d_in[11];
  const float* gkv   = (const float*)d_in[12];
  const float* betakv= (const float*)d_in[13];
  (void)in_sizes; (void)n_in; (void)out_size; (void)ws_size;

  char* ws = (char*)d_ws;
  const size_t MB = (size_t)1 << 20;
  u16* qn  = (u16*)(ws + 0 * MB);
  u16* cn  = (u16*)(ws + 8 * MB);
  u16* Wqt = (u16*)(ws + 16 * MB);
  u16* Wkt = (u16*)(ws + 18 * MB);
  u16* Wvt = (u16*)(ws + 20 * MB);
  u16* Wot = (u16*)(ws + 22 * MB);
  u16* Qb  = (u16*)(ws + 24 * MB);
  u16* Kb  = (u16*)(ws + 32 * MB);
  u16* Vtb = (u16*)(ws + 40 * MB);
  u16* AOb = (u16*)(ws + 48 * MB);

  ln_kernel<<<4096, 256, 0, stream>>>(query, gq, betaq, qn);
  ln_kernel<<<4096, 256, 0, stream>>>(context, gkv, betakv, cn);
  wtrans_kernel<<<dim3(32, 32, 4), 256, 0, stream>>>(Wq, Wk, Wv, Wo, Wqt, Wkt, Wvt, Wot);

  GArg3 a3;
  a3.g[0] = { qn, Wqt, bq, (void*)Qb,  nullptr, 1 };
  a3.g[1] = { cn, Wkt, bk, (void*)Kb,  nullptr, 0 };
  a3.g[2] = { cn, Wvt, bv, (void*)Vtb, nullptr, 2 };
  gemm128<<<dim3(32, 8, 3), 256, 0, stream>>>(a3);

  flash_kernel<<<dim3(32, 32), 128, 0, stream>>>(Qb, Kb, Vtb, AOb);

  GArg3 ao;
  ao.g[0] = { AOb, Wot, bo, d_out, query, 3 };
  ao.g[1] = ao.g[0];
  ao.g[2] = ao.g[0];
  gemm128<<<dim3(32, 8, 1), 256, 0, stream>>>(ao);
}

// Round 3
// 248.856 us; speedup vs baseline: 1.4247x; 1.1505x over previous
//
#include <hip/hip_runtime.h>
#include <hip/hip_bf16.h>

typedef unsigned short u16;
typedef unsigned long long u64;
typedef __bf16 bf16x8 __attribute__((ext_vector_type(8)));
typedef float f32x4 __attribute__((ext_vector_type(4)));

#define DIM 1024
#define NH 16
#define HD 64
// 0.125 * log2(e): folds the 1/sqrt(64) score scale and the exp->exp2 change of base
#define QSCALE 0.180336880972788f

__device__ __forceinline__ u16 f2bf(float f) {
  union { float f; unsigned u; } v; v.f = f;
  unsigned r = v.u + 0x7fffu + ((v.u >> 16) & 1u);
  return (u16)(r >> 16);
}

__device__ __forceinline__ unsigned pk2(float a, float b) {
  union { __hip_bfloat162 h; unsigned u; } cv;
  cv.h = __float22bfloat162_rn(make_float2(a, b));
  return cv.u;
}

__device__ __forceinline__ void gld16(const u16* gp, u16* lp) {
  __builtin_amdgcn_global_load_lds(
      (const __attribute__((address_space(1))) unsigned int*)(const void*)gp,
      (__attribute__((address_space(3))) unsigned int*)(void*)lp, 16, 0, 0);
}

// ---------------- Fused prep: 2x LayerNorm + 4x weight transpose ----------------
__global__ __launch_bounds__(256) void prep_kernel(
    const float* __restrict__ q, const float* __restrict__ c,
    const float* __restrict__ gq, const float* __restrict__ bq,
    const float* __restrict__ gkv, const float* __restrict__ bkv,
    u16* __restrict__ qn, u16* __restrict__ cn,
    const float* W0, const float* W1, const float* W2, const float* W3,
    u16* O0, u16* O1, u16* O2, u16* O3) {
  __shared__ float red[2][4];
  __shared__ float t[32][33];
  int bid = blockIdx.x, tid = threadIdx.x;
  if (bid < 8192) {
    const float* x  = bid < 4096 ? q : c;
    const float* g  = bid < 4096 ? gq : gkv;
    const float* be = bid < 4096 ? bq : bkv;
    u16* out = bid < 4096 ? qn : cn;
    int row = bid & 4095;
    float4 v = ((const float4*)(x + (size_t)row * DIM))[tid];
    float s1 = v.x + v.y + v.z + v.w;
    float s2 = v.x * v.x + v.y * v.y + v.z * v.z + v.w * v.w;
#pragma unroll
    for (int o = 32; o >= 1; o >>= 1) { s1 += __shfl_xor(s1, o, 64); s2 += __shfl_xor(s2, o, 64); }
    int wv = tid >> 6;
    if ((tid & 63) == 0) { red[0][wv] = s1; red[1][wv] = s2; }
    __syncthreads();
    s1 = red[0][0] + red[0][1] + red[0][2] + red[0][3];
    s2 = red[1][0] + red[1][1] + red[1][2] + red[1][3];
    float mu = s1 * (1.f / DIM);
    float var = s2 * (1.f / DIM) - mu * mu;
    float rs = rsqrtf(var + 1e-5f);
    float4 gv = ((const float4*)g)[tid];
    float4 bv = ((const float4*)be)[tid];
    uint2 o2;
    o2.x = pk2((v.x - mu) * rs * gv.x + bv.x, (v.y - mu) * rs * gv.y + bv.y);
    o2.y = pk2((v.z - mu) * rs * gv.z + bv.z, (v.w - mu) * rs * gv.w + bv.w);
    ((uint2*)(out + (size_t)row * DIM))[tid] = o2;
  } else {
    int wid = bid - 8192;
    int z = wid >> 10;
    const float* W = z == 0 ? W0 : z == 1 ? W1 : z == 2 ? W2 : W3;
    u16* O        = z == 0 ? O0 : z == 1 ? O1 : z == 2 ? O2 : O3;
    int xy = wid & 1023;
    int bx = (xy & 31) * 32, by = (xy >> 5) * 32;
    int tx = tid & 31, ty = tid >> 5;
#pragma unroll
    for (int i = 0; i < 4; ++i) t[ty + i * 8][tx] = W[(size_t)(by + ty + i * 8) * DIM + bx + tx];
    __syncthreads();
#pragma unroll
    for (int i = 0; i < 4; ++i) O[(size_t)(bx + ty + i * 8) * DIM + by + tx] = f2bf(t[tx][ty + i * 8]);
  }
}

// ---------------- 128x64 bf16 MFMA GEMM ----------------
// mode 0: bf16 row-major (K proj) | 1: bf16 *QSCALE (Q proj)
// mode 2: bf16 transposed per batch: out[(b*1024+n)*2048 + t] (V proj -> Vt)
// mode 3: fp32 row-major + bias + residual (O proj)
struct GArg { const u16* A; const u16* Bt; const float* bias; void* out; const float* resid; int mode; };
struct GArg3 { GArg g[3]; };

__global__ __launch_bounds__(256) void gemm128(GArg3 args) {
  GArg ga = args.g[blockIdx.z];
  const u16* __restrict__ A  = ga.A;
  const u16* __restrict__ Bt = ga.Bt;
  __shared__ __align__(16) u16 sm[(128 + 64) * 64];
  u16* As = sm;             // 128x64
  u16* Bs = sm + 128 * 64;  // 64x64
  int tid = threadIdx.x, wave = tid >> 6, lane = tid & 63;
  int lr = lane & 15, quad = lane >> 4;
  int m0 = blockIdx.x * 128, n0 = blockIdx.y * 64;
  int wm = (wave >> 1) * 64, wn = (wave & 1) * 32;
  f32x4 acc[4][2] = {};
  for (int kt = 0; kt < DIM; kt += 64) {
#pragma unroll
    for (int r = 0; r < 4; ++r) {
      int slot = tid + r * 256;
      int row = slot >> 3;
      int c = (slot & 7) ^ (row & 7);
      gld16(A + (size_t)(m0 + row) * DIM + kt + c * 8, &As[slot * 8]);
    }
#pragma unroll
    for (int r = 0; r < 2; ++r) {
      int slot = tid + r * 256;
      int row = slot >> 3;
      int c = (slot & 7) ^ (row & 7);
      gld16(Bt + (size_t)(n0 + row) * DIM + kt + c * 8, &Bs[slot * 8]);
    }
    __syncthreads();
#pragma unroll
    for (int kc = 0; kc < 2; ++kc) {
      int pc = ((kc * 4 + quad) ^ (lr & 7)) * 8;
      bf16x8 af[4], bfr[2];
#pragma unroll
      for (int i = 0; i < 4; ++i) af[i] = *(const bf16x8*)&As[(wm + i * 16 + lr) * 64 + pc];
#pragma unroll
      for (int j = 0; j < 2; ++j) bfr[j] = *(const bf16x8*)&Bs[(wn + j * 16 + lr) * 64 + pc];
#pragma unroll
      for (int mi = 0; mi < 4; ++mi)
#pragma unroll
        for (int ni = 0; ni < 2; ++ni)
          acc[mi][ni] = __builtin_amdgcn_mfma_f32_16x16x32_bf16(af[mi], bfr[ni], acc[mi][ni], 0, 0, 0);
    }
    __syncthreads();
  }
  int mode = ga.mode;
  const float* bias = ga.bias;
#pragma unroll
  for (int mi = 0; mi < 4; ++mi)
#pragma unroll
    for (int ni = 0; ni < 2; ++ni) {
      int col = n0 + wn + ni * 16 + lr;
      float bv = bias[col];
      int row0 = m0 + wm + mi * 16 + quad * 4;
      if (mode == 2) {
        int bb = row0 >> 11, t0 = row0 & 2047;
        u64 pk = 0;
#pragma unroll
        for (int r = 0; r < 4; ++r)
          pk |= (u64)f2bf(acc[mi][ni][r] + bv) << (16 * r);
        *(u64*)&((u16*)ga.out)[((size_t)(bb << 10) + col) * 2048 + t0] = pk;
      } else if (mode == 3) {
#pragma unroll
        for (int r = 0; r < 4; ++r) {
          int row = row0 + r;
          ((float*)ga.out)[(size_t)row * DIM + col] =
              acc[mi][ni][r] + bv + ga.resid[(size_t)row * DIM + col];
        }
      } else {
        float sc = (mode == 1) ? QSCALE : 1.f;
#pragma unroll
        for (int r = 0; r < 4; ++r)
          ((u16*)ga.out)[(size_t)(row0 + r) * DIM + col] = f2bf((acc[mi][ni][r] + bv) * sc);
      }
    }
}

// ---------------- Flash attention: 4 waves, 128 q/block, double-buffered K/V ----------
// Q,K: [B*2048,1024] bf16 (Q pre-scaled). Vt: [(b*1024+h*64+d)][token] bf16.
#define FK0 0
#define FV0 4096
#define FK1 8192
#define FV1 12288
#define FQP 16384  // Q staging (128x64), aliased per-wave by P after Q-frag hoist
__global__ __launch_bounds__(256) void flash_kernel(const u16* __restrict__ Q,
    const u16* __restrict__ Kg, const u16* __restrict__ Vt, u16* __restrict__ AO) {
  __shared__ __align__(16) u16 lds[24576];  // 48 KB
  int tid = threadIdx.x, wave = tid >> 6, lane = tid & 63;
  int lr = lane & 15, quad = lane >> 4;
  int bh = blockIdx.x, b = bh >> 4, h = bh & 15;
  int q0 = blockIdx.y * 128;

  const u16* qbase = Q + (size_t)(b * 2048 + q0) * DIM + h * HD;
  const u16* kbase = Kg + (size_t)(b * 2048) * DIM + h * HD;
  const u16* vbase = Vt + (size_t)(b * 1024 + h * HD) * 2048;

  // stage Q (128x64) and K/V tile 0 into buffer 0
#pragma unroll
  for (int r = 0; r < 4; ++r) {
    int slot = tid + r * 256;
    int row = slot >> 3;
    int c = (slot & 7) ^ (row & 7);
    gld16(qbase + (size_t)row * DIM + c * 8, &lds[FQP + slot * 8]);
  }
#pragma unroll
  for (int r = 0; r < 2; ++r) {
    int slot = tid + r * 256;
    int row = slot >> 3;
    int c = (slot & 7) ^ (row & 7);
    gld16(kbase + (size_t)row * DIM + c * 8, &lds[FK0 + slot * 8]);
    gld16(vbase + (size_t)row * 2048 + c * 8, &lds[FV0 + slot * 8]);
  }
  __syncthreads();

  bf16x8 qf[2][2];
#pragma unroll
  for (int s = 0; s < 2; ++s)
#pragma unroll
    for (int kc = 0; kc < 2; ++kc)
      qf[s][kc] = *(const bf16x8*)&lds[FQP + (wave * 32 + s * 16 + lr) * 64 +
                                       (((kc * 4 + quad) ^ (lr & 7)) * 8)];

  int pb = FQP + wave * 2048;  // per-wave P region (32x64), aliases own Q rows only
  float plsum[2] = {0.f, 0.f};
  f32x4 oacc[2][4] = {};

  for (int j = 0; j < 32; ++j) {
    int cb = (j & 1) ? FK1 : FK0;  // current K base; V = cb + 4096
    if (j < 31) {
      int nb = (j & 1) ? FK0 : FK1;
      int nj = j * 64 + 64;
#pragma unroll
      for (int r = 0; r < 2; ++r) {
        int slot = tid + r * 256;
        int row = slot >> 3;
        int c = (slot & 7) ^ (row & 7);
        gld16(kbase + (size_t)(nj + row) * DIM + c * 8, &lds[nb + slot * 8]);
        gld16(vbase + (size_t)row * 2048 + nj + c * 8, &lds[nb + 4096 + slot * 8]);
      }
    }

    // S^T = K . Q^T
    f32x4 sf[2][4] = {};
#pragma unroll
    for (int kc = 0; kc < 2; ++kc) {
      int pc = ((kc * 4 + quad) ^ (lr & 7)) * 8;
#pragma unroll
      for (int ns = 0; ns < 4; ++ns) {
        bf16x8 kf = *(const bf16x8*)&lds[cb + (ns * 16 + lr) * 64 + pc];
#pragma unroll
        for (int s = 0; s < 2; ++s)
          sf[s][ns] = __builtin_amdgcn_mfma_f32_16x16x32_bf16(kf, qf[s][kc], sf[s][ns], 0, 0, 0);
      }
    }

    // p = exp2(s); pack 4 consecutive k -> one 8B LDS write into wave-private P
#pragma unroll
    for (int s = 0; s < 2; ++s)
#pragma unroll
      for (int ns = 0; ns < 4; ++ns) {
        float p0 = exp2f(sf[s][ns][0]), p1 = exp2f(sf[s][ns][1]);
        float p2 = exp2f(sf[s][ns][2]), p3 = exp2f(sf[s][ns][3]);
        plsum[s] += (p0 + p1) + (p2 + p3);
        uint2 pk;
        pk.x = pk2(p0, p1);
        pk.y = pk2(p2, p3);
        int chunk = ns * 2 + (quad >> 1);
        int off = pb + (s * 16 + lr) * 64 + ((chunk ^ (lr & 7)) * 8) + (quad & 1) * 4;
        *(uint2*)&lds[off] = pk;
      }
    __threadfence_block();  // intra-wave P write -> read ordering

    // O^T += V^T . P^T
#pragma unroll
    for (int kc = 0; kc < 2; ++kc) {
      int pc = ((kc * 4 + quad) ^ (lr & 7)) * 8;
      bf16x8 pf[2];
#pragma unroll
      for (int s = 0; s < 2; ++s)
        pf[s] = *(const bf16x8*)&lds[pb + (s * 16 + lr) * 64 + pc];
#pragma unroll
      for (int ds = 0; ds < 4; ++ds) {
        bf16x8 vf = *(const bf16x8*)&lds[cb + 4096 + (ds * 16 + lr) * 64 + pc];
#pragma unroll
        for (int s = 0; s < 2; ++s)
          oacc[s][ds] = __builtin_amdgcn_mfma_f32_16x16x32_bf16(vf, pf[s], oacc[s][ds], 0, 0, 0);
      }
    }
    __syncthreads();  // buffer swap point; also drains next-tile gld16
  }

#pragma unroll
  for (int s = 0; s < 2; ++s) {
    float l = plsum[s];
    l += __shfl_xor(l, 16, 64);
    l += __shfl_xor(l, 32, 64);
    float rl = 1.f / l;
    size_t qrow = (size_t)(b * 2048 + q0 + wave * 32 + s * 16 + lr);
#pragma unroll
    for (int ds = 0; ds < 4; ++ds) {
      uint2 pk;
      pk.x = pk2(oacc[s][ds][0] * rl, oacc[s][ds][1] * rl);
      pk.y = pk2(oacc[s][ds][2] * rl, oacc[s][ds][3] * rl);
      *(uint2*)&AO[qrow * DIM + h * HD + ds * 16 + quad * 4] = pk;
    }
  }
}

extern "C" void kernel_launch(void* const* d_in, const int* in_sizes, int n_in,
                              void* d_out, int out_size, void* d_ws, size_t ws_size,
                              hipStream_t stream) {
  const float* query   = (const float*)d_in[0];
  const float* context = (const float*)d_in[1];
  const float* Wq = (const float*)d_in[2];
  const float* bq = (const float*)d_in[3];
  const float* Wk = (const float*)d_in[4];
  const float* bk = (const float*)d_in[5];
  const float* Wv = (const float*)d_in[6];
  const float* bv = (const float*)d_in[7];
  const float* Wo = (const float*)d_in[8];
  const float* bo = (const float*)d_in[9];
  const float* gq    = (const float*)d_in[10];
  const float* betaq = (const float*)d_in[11];
  const float* gkv   = (const float*)d_in[12];
  const float* betakv= (const float*)d_in[13];
  (void)in_sizes; (void)n_in; (void)out_size; (void)ws_size;

  char* ws = (char*)d_ws;
  const size_t MB = (size_t)1 << 20;
  u16* qn  = (u16*)(ws + 0 * MB);
  u16* cn  = (u16*)(ws + 8 * MB);
  u16* Wqt = (u16*)(ws + 16 * MB);
  u16* Wkt = (u16*)(ws + 18 * MB);
  u16* Wvt = (u16*)(ws + 20 * MB);
  u16* Wot = (u16*)(ws + 22 * MB);
  u16* Qb  = (u16*)(ws + 24 * MB);
  u16* Kb  = (u16*)(ws + 32 * MB);
  u16* Vtb = (u16*)(ws + 40 * MB);
  u16* AOb = (u16*)(ws + 48 * MB);

  prep_kernel<<<12288, 256, 0, stream>>>(query, context, gq, betaq, gkv, betakv,
                                         qn, cn, Wq, Wk, Wv, Wo, Wqt, Wkt, Wvt, Wot);

  GArg3 a3;
  a3.g[0] = { qn, Wqt, bq, (void*)Qb,  nullptr, 1 };
  a3.g[1] = { cn, Wkt, bk, (void*)Kb,  nullptr, 0 };
  a3.g[2] = { cn, Wvt, bv, (void*)Vtb, nullptr, 2 };
  gemm128<<<dim3(32, 16, 3), 256, 0, stream>>>(a3);

  flash_kernel<<<dim3(32, 16), 256, 0, stream>>>(Qb, Kb, Vtb, AOb);

  GArg3 ao;
  ao.g[0] = { AOb, Wot, bo, d_out, query, 3 };
  ao.g[1] = ao.g[0];
  ao.g[2] = ao.g[0];
  gemm128<<<dim3(32, 16, 1), 256, 0, stream>>>(ao);
}

// Round 4
// 244.857 us; speedup vs baseline: 1.4479x; 1.0163x over previous
//
#include <hip/hip_runtime.h>
#include <hip/hip_bf16.h>

typedef unsigned short u16;
typedef unsigned long long u64;
typedef __bf16 bf16x8 __attribute__((ext_vector_type(8)));
typedef float f32x4 __attribute__((ext_vector_type(4)));

#define DIM 1024
#define NH 16
#define HD 64
// 0.125 * log2(e): folds the 1/sqrt(64) score scale and the exp->exp2 change of base
#define QSCALE 0.180336880972788f

__device__ __forceinline__ u16 f2bf(float f) {
  union { float f; unsigned u; } v; v.f = f;
  unsigned r = v.u + 0x7fffu + ((v.u >> 16) & 1u);
  return (u16)(r >> 16);
}

__device__ __forceinline__ unsigned pk2(float a, float b) {
  union { __hip_bfloat162 h; unsigned u; } cv;
  cv.h = __float22bfloat162_rn(make_float2(a, b));
  return cv.u;
}

__device__ __forceinline__ float bf2f(unsigned s) {
  union { unsigned u; float f; } v; v.u = s << 16; return v.f;
}

__device__ __forceinline__ void gld16(const u16* gp, u16* lp) {
  __builtin_amdgcn_global_load_lds(
      (const __attribute__((address_space(1))) unsigned int*)(const void*)gp,
      (__attribute__((address_space(3))) unsigned int*)(void*)lp, 16, 0, 0);
}

// ---------------- Fused prep: 2x LayerNorm + 4x weight transpose ----------------
__global__ __launch_bounds__(256) void prep_kernel(
    const float* __restrict__ q, const float* __restrict__ c,
    const float* __restrict__ gq, const float* __restrict__ bq,
    const float* __restrict__ gkv, const float* __restrict__ bkv,
    u16* __restrict__ qn, u16* __restrict__ cn,
    const float* W0, const float* W1, const float* W2, const float* W3,
    u16* O0, u16* O1, u16* O2, u16* O3) {
  __shared__ float red[2][4];
  __shared__ float t[32][33];
  int bid = blockIdx.x, tid = threadIdx.x;
  if (bid < 8192) {
    const float* x  = bid < 4096 ? q : c;
    const float* g  = bid < 4096 ? gq : gkv;
    const float* be = bid < 4096 ? bq : bkv;
    u16* out = bid < 4096 ? qn : cn;
    int row = bid & 4095;
    float4 v = ((const float4*)(x + (size_t)row * DIM))[tid];
    float s1 = v.x + v.y + v.z + v.w;
    float s2 = v.x * v.x + v.y * v.y + v.z * v.z + v.w * v.w;
#pragma unroll
    for (int o = 32; o >= 1; o >>= 1) { s1 += __shfl_xor(s1, o, 64); s2 += __shfl_xor(s2, o, 64); }
    int wv = tid >> 6;
    if ((tid & 63) == 0) { red[0][wv] = s1; red[1][wv] = s2; }
    __syncthreads();
    s1 = red[0][0] + red[0][1] + red[0][2] + red[0][3];
    s2 = red[1][0] + red[1][1] + red[1][2] + red[1][3];
    float mu = s1 * (1.f / DIM);
    float var = s2 * (1.f / DIM) - mu * mu;
    float rs = rsqrtf(var + 1e-5f);
    float4 gv = ((const float4*)g)[tid];
    float4 bv = ((const float4*)be)[tid];
    uint2 o2;
    o2.x = pk2((v.x - mu) * rs * gv.x + bv.x, (v.y - mu) * rs * gv.y + bv.y);
    o2.y = pk2((v.z - mu) * rs * gv.z + bv.z, (v.w - mu) * rs * gv.w + bv.w);
    ((uint2*)(out + (size_t)row * DIM))[tid] = o2;
  } else {
    int wid = bid - 8192;
    int z = wid >> 10;
    const float* W = z == 0 ? W0 : z == 1 ? W1 : z == 2 ? W2 : W3;
    u16* O        = z == 0 ? O0 : z == 1 ? O1 : z == 2 ? O2 : O3;
    int xy = wid & 1023;
    int bx = (xy & 31) * 32, by = (xy >> 5) * 32;
    int tx = tid & 31, ty = tid >> 5;
#pragma unroll
    for (int i = 0; i < 4; ++i) t[ty + i * 8][tx] = W[(size_t)(by + ty + i * 8) * DIM + bx + tx];
    __syncthreads();
#pragma unroll
    for (int i = 0; i < 4; ++i) O[(size_t)(bx + ty + i * 8) * DIM + by + tx] = f2bf(t[tx][ty + i * 8]);
  }
}

// ---------------- 128x128 bf16 MFMA GEMM (QKV fused) ----------------
// mode 0: bf16 row-major (K proj) | 1: bf16 *QSCALE (Q proj)
// mode 2: bf16 transposed per batch: out[(b*1024+n)*2048 + t] (V proj -> Vt)
struct GArg { const u16* A; const u16* Bt; const float* bias; void* out; int mode; };
struct GArg3 { GArg g[3]; };

__global__ __launch_bounds__(256) void gemm128(GArg3 args) {
  GArg ga = args.g[blockIdx.z];
  const u16* __restrict__ A  = ga.A;
  const u16* __restrict__ Bt = ga.Bt;
  __shared__ __align__(16) u16 sm[128 * 64 * 2];
  u16* As = sm;
  u16* Bs = sm + 128 * 64;
  int tid = threadIdx.x, wave = tid >> 6, lane = tid & 63;
  int lr = lane & 15, quad = lane >> 4;
  int m0 = blockIdx.x * 128, n0 = blockIdx.y * 128;
  int wm = (wave >> 1) * 64, wn = (wave & 1) * 64;
  f32x4 acc[4][4] = {};
  for (int kt = 0; kt < DIM; kt += 64) {
#pragma unroll
    for (int r = 0; r < 4; ++r) {
      int slot = tid + r * 256;
      int row = slot >> 3;
      int c = (slot & 7) ^ (row & 7);
      gld16(A + (size_t)(m0 + row) * DIM + kt + c * 8, &As[slot * 8]);
    }
#pragma unroll
    for (int r = 0; r < 4; ++r) {
      int slot = tid + r * 256;
      int row = slot >> 3;
      int c = (slot & 7) ^ (row & 7);
      gld16(Bt + (size_t)(n0 + row) * DIM + kt + c * 8, &Bs[slot * 8]);
    }
    __syncthreads();
#pragma unroll
    for (int kc = 0; kc < 2; ++kc) {
      int pc = ((kc * 4 + quad) ^ (lr & 7)) * 8;
      bf16x8 af[4], bfr[4];
#pragma unroll
      for (int i = 0; i < 4; ++i) {
        af[i]  = *(const bf16x8*)&As[(wm + i * 16 + lr) * 64 + pc];
        bfr[i] = *(const bf16x8*)&Bs[(wn + i * 16 + lr) * 64 + pc];
      }
#pragma unroll
      for (int mi = 0; mi < 4; ++mi)
#pragma unroll
        for (int ni = 0; ni < 4; ++ni)
          acc[mi][ni] = __builtin_amdgcn_mfma_f32_16x16x32_bf16(af[mi], bfr[ni], acc[mi][ni], 0, 0, 0);
    }
    __syncthreads();
  }
  int mode = ga.mode;
  const float* bias = ga.bias;
#pragma unroll
  for (int mi = 0; mi < 4; ++mi)
#pragma unroll
    for (int ni = 0; ni < 4; ++ni) {
      int col = n0 + wn + ni * 16 + lr;
      float bv = bias[col];
      int row0 = m0 + wm + mi * 16 + quad * 4;
      if (mode == 2) {
        int bb = row0 >> 11, t0 = row0 & 2047;
        u64 pk = 0;
#pragma unroll
        for (int r = 0; r < 4; ++r)
          pk |= (u64)f2bf(acc[mi][ni][r] + bv) << (16 * r);
        *(u64*)&((u16*)ga.out)[((size_t)(bb << 10) + col) * 2048 + t0] = pk;
      } else {
        float sc = (mode == 1) ? QSCALE : 1.f;
#pragma unroll
        for (int r = 0; r < 4; ++r)
          ((u16*)ga.out)[(size_t)(row0 + r) * DIM + col] = f2bf((acc[mi][ni][r] + bv) * sc);
      }
    }
}

// ---------------- 128x64 GEMM, fp32 out + bias + residual (O proj) ----------------
__global__ __launch_bounds__(256) void gemm_o(const u16* __restrict__ A,
    const u16* __restrict__ Bt, const float* __restrict__ bias,
    float* __restrict__ out, const float* __restrict__ resid) {
  __shared__ __align__(16) u16 sm[(128 + 64) * 64];
  u16* As = sm;
  u16* Bs = sm + 128 * 64;
  int tid = threadIdx.x, wave = tid >> 6, lane = tid & 63;
  int lr = lane & 15, quad = lane >> 4;
  int m0 = blockIdx.x * 128, n0 = blockIdx.y * 64;
  int wm = (wave >> 1) * 64, wn = (wave & 1) * 32;
  f32x4 acc[4][2] = {};
  for (int kt = 0; kt < DIM; kt += 64) {
#pragma unroll
    for (int r = 0; r < 4; ++r) {
      int slot = tid + r * 256;
      int row = slot >> 3;
      int c = (slot & 7) ^ (row & 7);
      gld16(A + (size_t)(m0 + row) * DIM + kt + c * 8, &As[slot * 8]);
    }
#pragma unroll
    for (int r = 0; r < 2; ++r) {
      int slot = tid + r * 256;
      int row = slot >> 3;
      int c = (slot & 7) ^ (row & 7);
      gld16(Bt + (size_t)(n0 + row) * DIM + kt + c * 8, &Bs[slot * 8]);
    }
    __syncthreads();
#pragma unroll
    for (int kc = 0; kc < 2; ++kc) {
      int pc = ((kc * 4 + quad) ^ (lr & 7)) * 8;
      bf16x8 af[4], bfr[2];
#pragma unroll
      for (int i = 0; i < 4; ++i) af[i] = *(const bf16x8*)&As[(wm + i * 16 + lr) * 64 + pc];
#pragma unroll
      for (int j = 0; j < 2; ++j) bfr[j] = *(const bf16x8*)&Bs[(wn + j * 16 + lr) * 64 + pc];
#pragma unroll
      for (int mi = 0; mi < 4; ++mi)
#pragma unroll
        for (int ni = 0; ni < 2; ++ni)
          acc[mi][ni] = __builtin_amdgcn_mfma_f32_16x16x32_bf16(af[mi], bfr[ni], acc[mi][ni], 0, 0, 0);
    }
    __syncthreads();
  }
#pragma unroll
  for (int mi = 0; mi < 4; ++mi)
#pragma unroll
    for (int ni = 0; ni < 2; ++ni) {
      int col = n0 + wn + ni * 16 + lr;
      float bv = bias[col];
      int row0 = m0 + wm + mi * 16 + quad * 4;
#pragma unroll
      for (int r = 0; r < 4; ++r) {
        int row = row0 + r;
        out[(size_t)row * DIM + col] = acc[mi][ni][r] + bv + resid[(size_t)row * DIM + col];
      }
    }
}

// ---------------- Flash attention, split-K x2, double-buffered K/V ----------------
// Q,K: [B*2048,1024] bf16 (Q pre-scaled). Vt: [(b*1024+h*64+d)][token] bf16.
// Each block: 4 waves, 128 q-rows, 16 j-tiles (1024 tokens). Outputs unnormalized
// bf16 O-partial + fp32 row-sum l (no-max exp2 softmax => partials add exactly).
#define FK0 0
#define FV0 4096
#define FK1 8192
#define FV1 12288
#define FQP 16384
__global__ __launch_bounds__(256) void flash_kernel(const u16* __restrict__ Q,
    const u16* __restrict__ Kg, const u16* __restrict__ Vt,
    u16* __restrict__ O0, u16* __restrict__ O1,
    float* __restrict__ L0, float* __restrict__ L1) {
  __shared__ __align__(16) u16 lds[24576];  // 48 KB
  int tid = threadIdx.x, wave = tid >> 6, lane = tid & 63;
  int lr = lane & 15, quad = lane >> 4;
  int bh = blockIdx.x, b = bh >> 4, h = bh & 15;
  int q0 = blockIdx.y * 128;
  int split = blockIdx.z;
  u16* Op = split ? O1 : O0;
  float* Lp = split ? L1 : L0;
  int t0 = split * 1024;

  const u16* qbase = Q + (size_t)(b * 2048 + q0) * DIM + h * HD;
  const u16* kbase = Kg + (size_t)(b * 2048 + t0) * DIM + h * HD;
  const u16* vbase = Vt + (size_t)(b * 1024 + h * HD) * 2048 + t0;

#pragma unroll
  for (int r = 0; r < 4; ++r) {
    int slot = tid + r * 256;
    int row = slot >> 3;
    int c = (slot & 7) ^ (row & 7);
    gld16(qbase + (size_t)row * DIM + c * 8, &lds[FQP + slot * 8]);
  }
#pragma unroll
  for (int r = 0; r < 2; ++r) {
    int slot = tid + r * 256;
    int row = slot >> 3;
    int c = (slot & 7) ^ (row & 7);
    gld16(kbase + (size_t)row * DIM + c * 8, &lds[FK0 + slot * 8]);
    gld16(vbase + (size_t)row * 2048 + c * 8, &lds[FV0 + slot * 8]);
  }
  __syncthreads();

  bf16x8 qf[2][2];
#pragma unroll
  for (int s = 0; s < 2; ++s)
#pragma unroll
    for (int kc = 0; kc < 2; ++kc)
      qf[s][kc] = *(const bf16x8*)&lds[FQP + (wave * 32 + s * 16 + lr) * 64 +
                                       (((kc * 4 + quad) ^ (lr & 7)) * 8)];

  int pb = FQP + wave * 2048;  // per-wave P region (32x64), aliases own Q rows
  float plsum[2] = {0.f, 0.f};
  f32x4 oacc[2][4] = {};

  for (int j = 0; j < 16; ++j) {
    int cb = (j & 1) ? FK1 : FK0;
    if (j < 15) {
      int nb = (j & 1) ? FK0 : FK1;
      int nj = j * 64 + 64;
#pragma unroll
      for (int r = 0; r < 2; ++r) {
        int slot = tid + r * 256;
        int row = slot >> 3;
        int c = (slot & 7) ^ (row & 7);
        gld16(kbase + (size_t)(nj + row) * DIM + c * 8, &lds[nb + slot * 8]);
        gld16(vbase + (size_t)row * 2048 + nj + c * 8, &lds[nb + 4096 + slot * 8]);
      }
    }

    // S^T = K . Q^T
    f32x4 sf[2][4] = {};
#pragma unroll
    for (int kc = 0; kc < 2; ++kc) {
      int pc = ((kc * 4 + quad) ^ (lr & 7)) * 8;
#pragma unroll
      for (int ns = 0; ns < 4; ++ns) {
        bf16x8 kf = *(const bf16x8*)&lds[cb + (ns * 16 + lr) * 64 + pc];
#pragma unroll
        for (int s = 0; s < 2; ++s)
          sf[s][ns] = __builtin_amdgcn_mfma_f32_16x16x32_bf16(kf, qf[s][kc], sf[s][ns], 0, 0, 0);
      }
    }

    // p = exp2(s); 4 consecutive k per lane -> one 8B LDS write into wave-private P
#pragma unroll
    for (int s = 0; s < 2; ++s)
#pragma unroll
      for (int ns = 0; ns < 4; ++ns) {
        float p0 = exp2f(sf[s][ns][0]), p1 = exp2f(sf[s][ns][1]);
        float p2 = exp2f(sf[s][ns][2]), p3 = exp2f(sf[s][ns][3]);
        plsum[s] += (p0 + p1) + (p2 + p3);
        uint2 pk;
        pk.x = pk2(p0, p1);
        pk.y = pk2(p2, p3);
        int chunk = ns * 2 + (quad >> 1);
        int off = pb + (s * 16 + lr) * 64 + ((chunk ^ (lr & 7)) * 8) + (quad & 1) * 4;
        *(uint2*)&lds[off] = pk;
      }
    __threadfence_block();

    // O^T += V^T . P^T
#pragma unroll
    for (int kc = 0; kc < 2; ++kc) {
      int pc = ((kc * 4 + quad) ^ (lr & 7)) * 8;
      bf16x8 pf[2];
#pragma unroll
      for (int s = 0; s < 2; ++s)
        pf[s] = *(const bf16x8*)&lds[pb + (s * 16 + lr) * 64 + pc];
#pragma unroll
      for (int ds = 0; ds < 4; ++ds) {
        bf16x8 vf = *(const bf16x8*)&lds[cb + 4096 + (ds * 16 + lr) * 64 + pc];
#pragma unroll
        for (int s = 0; s < 2; ++s)
          oacc[s][ds] = __builtin_amdgcn_mfma_f32_16x16x32_bf16(vf, pf[s], oacc[s][ds], 0, 0, 0);
      }
    }
    __syncthreads();
  }

#pragma unroll
  for (int s = 0; s < 2; ++s) {
    float l = plsum[s];
    l += __shfl_xor(l, 16, 64);
    l += __shfl_xor(l, 32, 64);
    size_t qrow = (size_t)(b * 2048 + q0 + wave * 32 + s * 16 + lr);
    if (quad == 0) Lp[qrow * 16 + h] = l;
#pragma unroll
    for (int ds = 0; ds < 4; ++ds) {
      uint2 pk;
      pk.x = pk2(oacc[s][ds][0], oacc[s][ds][1]);
      pk.y = pk2(oacc[s][ds][2], oacc[s][ds][3]);
      *(uint2*)&Op[qrow * DIM + h * HD + ds * 16 + quad * 4] = pk;
    }
  }
}

// ---------------- Combine split-K partials -> normalized bf16 AO ----------------
__global__ __launch_bounds__(256) void combine_kernel(const u16* __restrict__ O0,
    const u16* __restrict__ O1, const float* __restrict__ L0, const float* __restrict__ L1,
    u16* __restrict__ AO) {
  int row = blockIdx.x, tid = threadIdx.x;
  int h = tid >> 4;
  float rl = 1.f / (L0[row * 16 + h] + L1[row * 16 + h]);
  uint2 a = ((const uint2*)(O0 + (size_t)row * DIM))[tid];
  uint2 b = ((const uint2*)(O1 + (size_t)row * DIM))[tid];
  float v0 = (bf2f(a.x & 0xffff) + bf2f(b.x & 0xffff)) * rl;
  float v1 = (bf2f(a.x >> 16)    + bf2f(b.x >> 16))    * rl;
  float v2 = (bf2f(a.y & 0xffff) + bf2f(b.y & 0xffff)) * rl;
  float v3 = (bf2f(a.y >> 16)    + bf2f(b.y >> 16))    * rl;
  uint2 o;
  o.x = pk2(v0, v1);
  o.y = pk2(v2, v3);
  ((uint2*)(AO + (size_t)row * DIM))[tid] = o;
}

extern "C" void kernel_launch(void* const* d_in, const int* in_sizes, int n_in,
                              void* d_out, int out_size, void* d_ws, size_t ws_size,
                              hipStream_t stream) {
  const float* query   = (const float*)d_in[0];
  const float* context = (const float*)d_in[1];
  const float* Wq = (const float*)d_in[2];
  const float* bq = (const float*)d_in[3];
  const float* Wk = (const float*)d_in[4];
  const float* bk = (const float*)d_in[5];
  const float* Wv = (const float*)d_in[6];
  const float* bv = (const float*)d_in[7];
  const float* Wo = (const float*)d_in[8];
  const float* bo = (const float*)d_in[9];
  const float* gq    = (const float*)d_in[10];
  const float* betaq = (const float*)d_in[11];
  const float* gkv   = (const float*)d_in[12];
  const float* betakv= (const float*)d_in[13];
  (void)in_sizes; (void)n_in; (void)out_size; (void)ws_size;

  char* ws = (char*)d_ws;
  const size_t MB = (size_t)1 << 20;
  u16* qn  = (u16*)(ws + 0 * MB);   // dead after QKV gemm; reused by Op0
  u16* cn  = (u16*)(ws + 8 * MB);   // dead after QKV gemm; reused by Op1
  u16* Wqt = (u16*)(ws + 16 * MB);  // dead after QKV; L0/L1 alias here
  u16* Wkt = (u16*)(ws + 18 * MB);
  u16* Wvt = (u16*)(ws + 20 * MB);
  u16* Wot = (u16*)(ws + 22 * MB);  // alive until O proj
  u16* Qb  = (u16*)(ws + 24 * MB);
  u16* Kb  = (u16*)(ws + 32 * MB);
  u16* Vtb = (u16*)(ws + 40 * MB);
  u16* AOb = (u16*)(ws + 48 * MB);
  u16* Op0 = qn;                        // 8 MB bf16 partial
  u16* Op1 = cn;                        // 8 MB bf16 partial
  float* L0 = (float*)(ws + 16 * MB);   // 256 KB (over dead Wqt)
  float* L1 = (float*)(ws + 16 * MB + 256 * 1024);

  prep_kernel<<<12288, 256, 0, stream>>>(query, context, gq, betaq, gkv, betakv,
                                         qn, cn, Wq, Wk, Wv, Wo, Wqt, Wkt, Wvt, Wot);

  GArg3 a3;
  a3.g[0] = { qn, Wqt, bq, (void*)Qb,  1 };
  a3.g[1] = { cn, Wkt, bk, (void*)Kb,  0 };
  a3.g[2] = { cn, Wvt, bv, (void*)Vtb, 2 };
  gemm128<<<dim3(32, 8, 3), 256, 0, stream>>>(a3);

  flash_kernel<<<dim3(32, 16, 2), 256, 0, stream>>>(Qb, Kb, Vtb, Op0, Op1, L0, L1);

  combine_kernel<<<4096, 256, 0, stream>>>(Op0, Op1, L0, L1, AOb);

  gemm_o<<<dim3(32, 16), 256, 0, stream>>>(AOb, Wot, bo, (float*)d_out, query);
}